// Round 1
// baseline (561.240 us; speedup 1.0000x reference)
//
#include <hip/hip_runtime.h>
#include <cstddef>

// Problem constants
#define NBATCH 16384
// XD=64, AD=16, NC=8, PEN=10 -> c = 1/(2*PEN) = 0.05, DELTA=1, ITERS=250

// ---------------------------------------------------------------------------
// Compile-time FISTA momentum coefficients beta_i = (t_i - 1)/t_{i+1}
// (data-independent sequence; reference carries tk starting at 1.0)
// ---------------------------------------------------------------------------
struct Betas {
  float b[250];
  static constexpr double csqrt(double x) {
    double g = x > 1.0 ? x : 1.0;
    for (int i = 0; i < 64; ++i) g = 0.5 * (g + x / g);
    return g;
  }
  constexpr Betas() : b{} {
    double tk = 1.0;
    for (int i = 0; i < 250; ++i) {
      double tk1 = 0.5 * (1.0 + csqrt(1.0 + 4.0 * tk * tk));
      b[i] = (float)((tk - 1.0) / tk1);
      tk = tk1;
    }
  }
};
__device__ constexpr Betas BETAS{};

// ---------------------------------------------------------------------------
// K1: gh[b][r] = Qc_flat[r][:] . x[b][:] + cc_flat[r],  r = m*64+i  (512 rows)
// One thread = one batch element x a 64-row chunk; W rows are wave-uniform
// (readfirstlane) -> scalar loads broadcast to all lanes. LDS transpose for
// fully coalesced [b][r] stores.
// ---------------------------------------------------------------------------
__global__ __launch_bounds__(256) void cbf_k1_gh(
    const float* __restrict__ Qc, const float* __restrict__ cc,
    const float* __restrict__ X, float* __restrict__ gh) {
  __shared__ float tile[64 * 132];  // [b-local 64][r-local 128 + pad 4]
  const int tid = threadIdx.x;
  const int e   = tid & 63;        // batch element within block
  const int rc  = tid >> 6;        // row chunk 0..3
  const int b0  = (blockIdx.x & 255) * 64;
  const int r0  = (blockIdx.x >> 8) * 256;

  float4 xr[16];
  const float4* xp = (const float4*)(X + (size_t)(b0 + e) * 64);
#pragma unroll
  for (int c = 0; c < 16; ++c) xr[c] = xp[c];

  const int rcu = __builtin_amdgcn_readfirstlane(rc);

  for (int p = 0; p < 2; ++p) {
    const int rbase = r0 + p * 128 + rcu * 32;
    const float* wbase = Qc + (size_t)rbase * 64;
#pragma unroll 4
    for (int rl = 0; rl < 32; ++rl) {
      const float4* w = (const float4*)(wbase + rl * 64);
      float a0 = 0.f, a1 = 0.f;
#pragma unroll
      for (int c = 0; c < 16; ++c) {
        float4 wv = w[c];
        a0 = fmaf(wv.x, xr[c].x, a0);
        a1 = fmaf(wv.y, xr[c].y, a1);
        a0 = fmaf(wv.z, xr[c].z, a0);
        a1 = fmaf(wv.w, xr[c].w, a1);
      }
      tile[e * 132 + rc * 32 + rl] = a0 + a1 + cc[rbase + rl];
    }
    __syncthreads();
    {
      const int c  = tid & 31;
      const int bq = tid >> 5;
#pragma unroll
      for (int bp = 0; bp < 8; ++bp) {
        const int bb = bp * 8 + bq;
        float4 v = *(const float4*)&tile[bb * 132 + c * 4];
        *(float4*)(gh + (size_t)(b0 + bb) * 512 + (r0 + p * 128) + c * 4) = v;
      }
    }
    __syncthreads();
  }
}

// ---------------------------------------------------------------------------
// K2: per-element setup. One wave (64 lanes) per element, 4 elements/block.
// Computes Ax, the dots x.gh_m / Ax.gh_m / cc_m.x -> bvec, then Lg = -gh^T B,
// S = 0.5 Lg Lg^T, qu = bvec - Lg a_des. Writes packets for K3.
// ---------------------------------------------------------------------------
#define ESTR  1800
#define XOFF  0
#define BVOFF 64
#define BOFF  72
#define GHOFF (72 + 1024)    // 1096, gh rows padded to 68
#define LGOFF (1096 + 544)   // 1640, Lg rows padded to 20

__global__ __launch_bounds__(256) void cbf_k2_setup(
    const float* __restrict__ X, const float* __restrict__ Abat,
    const float* __restrict__ Bbat, const float* __restrict__ cc,
    const float* __restrict__ dc, const float* __restrict__ a_des,
    const float* __restrict__ gh, float* __restrict__ S_ws,
    float* __restrict__ LgT_ws, float* __restrict__ qu_ws) {
  __shared__ float smem[4 * ESTR];
  const int tid  = threadIdx.x;
  const int sub  = tid >> 6;
  const int lane = tid & 63;
  const int b    = blockIdx.x * 4 + sub;
  float* sm = smem + sub * ESTR;

  // phase 0: stage x (for broadcast) and B (flat copy) into LDS
  const float xi = X[(size_t)b * 64 + lane];
  sm[XOFF + lane] = xi;
  {
    const float4* bp = (const float4*)(Bbat + (size_t)b * 1024);
#pragma unroll
    for (int n = 0; n < 4; ++n) {
      float4 v = bp[n * 64 + lane];
      *(float4*)&sm[BOFF + n * 256 + lane * 4] = v;
    }
  }
  __syncthreads();

  // phase A: ax = (A x)[lane]  (lane i owns row i of A)
  float ax = 0.f;
  {
    const float4* ap = (const float4*)(Abat + (size_t)b * 4096 + (size_t)lane * 64);
#pragma unroll
    for (int c = 0; c < 16; ++c) {
      float4 av = ap[c];
      float4 xv = *(const float4*)&sm[XOFF + 4 * c];  // LDS broadcast
      ax = fmaf(av.x, xv.x, ax);
      ax = fmaf(av.y, xv.y, ax);
      ax = fmaf(av.z, xv.z, ax);
      ax = fmaf(av.w, xv.w, ax);
    }
  }

  // phase B: per-m reductions -> g, bvec ; stage gh rows in LDS
#pragma unroll
  for (int m = 0; m < 8; ++m) {
    float ghm = gh[(size_t)b * 512 + m * 64 + lane];
    float ccm = cc[m * 64 + lane];
    sm[GHOFF + m * 68 + lane] = ghm;
    float p1 = xi * ghm;   // -> x . gh_m
    float p2 = ax * ghm;   // -> Ax . gh_m
    float p3 = ccm * xi;   // -> cc_m . x
#pragma unroll
    for (int s = 1; s < 64; s <<= 1) {
      p1 += __shfl_xor(p1, s);
      p2 += __shfl_xor(p2, s);
      p3 += __shfl_xor(p3, s);
    }
    // g = 0.5*x.u + cc.x - dc = 0.5*(x.gh + cc.x) - dc ;  h=-g
    // Lf = grad_h.Ax = -gh.Ax ;  bvec = -Lf - h = (Ax.gh) + g
    float g  = 0.5f * (p1 + p3) - dc[m];
    float bv = p2 + g;
    if (lane == 0) sm[BVOFF + m] = bv;
  }
  __syncthreads();

  // phase C: Lg[m][a] = -sum_i gh[m][i] * B[i][a] ; lane=(m, a-pair)
  const int mq  = lane >> 3;
  const int ap2 = lane & 7;
  float acc0 = 0.f, acc1 = 0.f;
#pragma unroll
  for (int c = 0; c < 16; ++c) {
    float4 gv = *(const float4*)&sm[GHOFF + mq * 68 + 4 * c];
#pragma unroll
    for (int n = 0; n < 4; ++n) {
      float2 bv2 = *(const float2*)&sm[BOFF + (4 * c + n) * 16 + 2 * ap2];
      float gvn = (n == 0) ? gv.x : ((n == 1) ? gv.y : ((n == 2) ? gv.z : gv.w));
      acc0 = fmaf(gvn, bv2.x, acc0);
      acc1 = fmaf(gvn, bv2.y, acc1);
    }
  }
  const float lg0 = -acc0, lg1 = -acc1;
  LgT_ws[(size_t)b * 128 + (2 * ap2) * 8 + mq]     = lg0;  // LgT[a][m]
  LgT_ws[(size_t)b * 128 + (2 * ap2 + 1) * 8 + mq] = lg1;
  sm[LGOFF + mq * 20 + 2 * ap2]     = lg0;
  sm[LGOFF + mq * 20 + 2 * ap2 + 1] = lg1;
  __syncthreads();

  // phase D: S[k][l] = 0.5 * sum_a Lg[k][a]*Lg[l][a] ; lane=(k,l)
  const int kq = lane >> 3;
  const int lq = lane & 7;
  float s = 0.f;
#pragma unroll
  for (int c = 0; c < 4; ++c) {
    float4 ka = *(const float4*)&sm[LGOFF + kq * 20 + 4 * c];
    float4 la = *(const float4*)&sm[LGOFF + lq * 20 + 4 * c];
    s = fmaf(ka.x, la.x, s);
    s = fmaf(ka.y, la.y, s);
    s = fmaf(ka.z, la.z, s);
    s = fmaf(ka.w, la.w, s);
  }
  S_ws[(size_t)b * 64 + kq * 8 + lq] = 0.5f * s;

  // phase E: qu[k] = bvec[k] - sum_a Lg[k][a]*a_des[a]
  float2 ad2 = *(const float2*)(a_des + (size_t)b * 16 + 2 * lq);
  float2 kg  = *(const float2*)&sm[LGOFF + kq * 20 + 2 * lq];
  float p = kg.x * ad2.x + kg.y * ad2.y;
  p += __shfl_xor(p, 1);
  p += __shfl_xor(p, 2);
  p += __shfl_xor(p, 4);
  float quv = sm[BVOFF + kq] - p;
  if (lq == 0) qu_ws[(size_t)b * 8 + kq] = quv;
}

// ---------------------------------------------------------------------------
// K3: dual FISTA, 8 lanes per element (lane k owns row k of S and lam[k]).
// M = [[S+cI, cI],[cI,cI]] -> grad_u = S yu + c(yu+yv) - qu ; grad_v = c(yu+yv)
// lambda_max(M) = ((2c+mu)+sqrt(4c^2+mu^2))/2 with mu = lambda_max(S) (power it.)
// ---------------------------------------------------------------------------
__global__ __launch_bounds__(256) void cbf_k3_fista(
    const float* __restrict__ S_ws, const float* __restrict__ qu_ws,
    const float* __restrict__ LgT_ws, const float* __restrict__ a_des,
    float* __restrict__ out) {
  const int gt = blockIdx.x * 256 + threadIdx.x;
  const int e  = gt >> 3;
  const int k  = gt & 7;

  const float4* Sp = (const float4*)(S_ws + (size_t)e * 64 + k * 8);
  const float4 sA = Sp[0];
  const float4 sB = Sp[1];
  const float qu = qu_ws[(size_t)e * 8 + k];

#define MV(vv, a0, a1)                              \
  a0 = sA.x * __shfl(vv, 0, 8);                     \
  a1 = sA.y * __shfl(vv, 1, 8);                     \
  a0 = fmaf(sA.z, __shfl(vv, 2, 8), a0);            \
  a1 = fmaf(sA.w, __shfl(vv, 3, 8), a1);            \
  a0 = fmaf(sB.x, __shfl(vv, 4, 8), a0);            \
  a1 = fmaf(sB.y, __shfl(vv, 5, 8), a1);            \
  a0 = fmaf(sB.z, __shfl(vv, 6, 8), a0);            \
  a1 = fmaf(sB.w, __shfl(vv, 7, 8), a1);

  // power iteration for mu = lambda_max(S)
  float v = 1.f;
  float a0, a1, sv;
#pragma unroll 4
  for (int it = 0; it < 40; ++it) {
    MV(v, a0, a1);
    sv = a0 + a1;
    float am = fabsf(sv);
    am = fmaxf(am, __shfl_xor(am, 1));
    am = fmaxf(am, __shfl_xor(am, 2));
    am = fmaxf(am, __shfl_xor(am, 4));
    v = sv / fmaxf(am, 1e-30f);
  }
  MV(v, a0, a1);
  sv = a0 + a1;
  float num = v * sv, den = v * v;
  num += __shfl_xor(num, 1); den += __shfl_xor(den, 1);
  num += __shfl_xor(num, 2); den += __shfl_xor(den, 2);
  num += __shfl_xor(num, 4); den += __shfl_xor(den, 4);
  float mu = (num / fmaxf(den, 1e-30f)) * 1.001f;  // small safety: keep t <= 1/L
  mu = fmaxf(mu, 0.f);
  const float lmax = 0.5f * ((0.1f + mu) + sqrtf(fmaf(mu, mu, 0.01f)));
  const float t = 1.0f / (lmax + 1e-6f);

  // FISTA, 250 iterations
  float yu = 0.f, yv = 0.f, lu = 0.f, lv = 0.f;
#pragma unroll 5
  for (int it = 0; it < 250; ++it) {
    const float beta = BETAS.b[it];
    const float w = 0.05f * (yu + yv);  // c*(yu+yv) = grad_v
    MV(yu, a0, a1);
    const float gu = (a0 + a1) + (w - qu);
    const float lun = fmaxf(fmaf(-t, gu, yu), 0.f);
    const float lvn = fmaxf(fmaf(-t, w, yv), 0.f);
    yu = fmaf(beta, lun - lu, lun); lu = lun;
    yv = fmaf(beta, lvn - lv, lvn); lv = lvn;
  }

  // primal recovery: a = a_des + 0.5 * Lg^T lam_u ; lane k writes a[2k],a[2k+1]
  const float4* Lp = (const float4*)(LgT_ws + (size_t)e * 128 + k * 16);
  const float4 g0 = Lp[0], g1 = Lp[1], g2 = Lp[2], g3 = Lp[3];
  const float r0[8] = {g0.x, g0.y, g0.z, g0.w, g1.x, g1.y, g1.z, g1.w};
  const float r1[8] = {g2.x, g2.y, g2.z, g2.w, g3.x, g3.y, g3.z, g3.w};
  float o0 = 0.f, o1 = 0.f;
#pragma unroll
  for (int l = 0; l < 8; ++l) {
    const float lamv = __shfl(lu, l, 8);
    o0 = fmaf(r0[l], lamv, o0);
    o1 = fmaf(r1[l], lamv, o1);
  }
  float2 ad = *(const float2*)(a_des + (size_t)e * 16 + 2 * k);
  float2 o;
  o.x = ad.x + 0.5f * o0;
  o.y = ad.y + 0.5f * o1;
  *(float2*)(out + (size_t)e * 16 + 2 * k) = o;
#undef MV
}

// ---------------------------------------------------------------------------
extern "C" void kernel_launch(void* const* d_in, const int* in_sizes, int n_in,
                              void* d_out, int out_size, void* d_ws, size_t ws_size,
                              hipStream_t stream) {
  (void)in_sizes; (void)n_in; (void)out_size; (void)ws_size;
  const float* a_des = (const float*)d_in[0];
  const float* x     = (const float*)d_in[1];
  const float* A     = (const float*)d_in[2];
  const float* B     = (const float*)d_in[3];
  const float* Qc    = (const float*)d_in[4];
  const float* cc    = (const float*)d_in[5];
  const float* dc    = (const float*)d_in[6];
  float* out = (float*)d_out;

  // workspace layout (floats): gh 16384*512 | S 16384*64 | LgT 16384*128 | qu 16384*8
  float* gh  = (float*)d_ws;
  float* S   = gh  + (size_t)NBATCH * 512;
  float* LgT = S   + (size_t)NBATCH * 64;
  float* qu  = LgT + (size_t)NBATCH * 128;

  hipLaunchKernelGGL(cbf_k1_gh, dim3(512), dim3(256), 0, stream, Qc, cc, x, gh);
  hipLaunchKernelGGL(cbf_k2_setup, dim3(4096), dim3(256), 0, stream,
                     x, A, B, cc, dc, a_des, gh, S, LgT, qu);
  hipLaunchKernelGGL(cbf_k3_fista, dim3(512), dim3(256), 0, stream,
                     S, qu, LgT, a_des, out);
}

// Round 2
// 540.421 us; speedup vs baseline: 1.0385x; 1.0385x over previous
//
#include <hip/hip_runtime.h>
#include <cstddef>

// Problem constants
#define NBATCH 16384
// XD=64, AD=16, NC=8, PEN=10 -> c = 1/(2*PEN) = 0.05, DELTA=1, ITERS=250

// ---------------------------------------------------------------------------
// Compile-time FISTA momentum coefficients beta_i = (t_i - 1)/t_{i+1}
// ---------------------------------------------------------------------------
struct Betas {
  float b[250];
  static constexpr double csqrt(double x) {
    double g = x > 1.0 ? x : 1.0;
    for (int i = 0; i < 64; ++i) g = 0.5 * (g + x / g);
    return g;
  }
  constexpr Betas() : b{} {
    double tk = 1.0;
    for (int i = 0; i < 250; ++i) {
      double tk1 = 0.5 * (1.0 + csqrt(1.0 + 4.0 * tk * tk));
      b[i] = (float)((tk - 1.0) / tk1);
      tk = tk1;
    }
  }
};
__device__ constexpr Betas BETAS{};

// DPP helpers: quad_perm ops on float (VALU pipe — no LDS/DS usage).
// broadcast lane j within quad: ctrl = j*0x55 ; xor1 = 0xB1 ; xor2 = 0x4E
template <int CTRL>
__device__ __forceinline__ float fdpp(float v) {
  return __int_as_float(
      __builtin_amdgcn_mov_dpp(__float_as_int(v), CTRL, 0xF, 0xF, true));
}

// ---------------------------------------------------------------------------
// K1: gh[b][r] = Qc_flat[r][:] . x[b][:] + cc_flat[r],  r = m*64+i  (512 rows)
// Thread = (batch element, 64-row chunk); Qc rows are wave-uniform (scalar
// broadcast loads). LDS transpose for coalesced [b][r] stores.
// ---------------------------------------------------------------------------
__global__ __launch_bounds__(256) void cbf_k1_gh(
    const float* __restrict__ Qc, const float* __restrict__ cc,
    const float* __restrict__ X, float* __restrict__ gh) {
  __shared__ float tile[64 * 132];  // [b-local 64][r-local 128 + pad 4]
  const int tid = threadIdx.x;
  const int e   = tid & 63;        // batch element within block
  const int rc  = tid >> 6;        // row chunk 0..3
  const int b0  = (blockIdx.x & 255) * 64;
  const int r0  = (blockIdx.x >> 8) * 256;

  float4 xr[16];
  const float4* xp = (const float4*)(X + (size_t)(b0 + e) * 64);
#pragma unroll
  for (int c = 0; c < 16; ++c) xr[c] = xp[c];

  const int rcu = __builtin_amdgcn_readfirstlane(rc);

  for (int p = 0; p < 2; ++p) {
    const int rbase = r0 + p * 128 + rcu * 32;
    const float* wbase = Qc + (size_t)rbase * 64;
#pragma unroll 4
    for (int rl = 0; rl < 32; ++rl) {
      const float4* w = (const float4*)(wbase + rl * 64);
      float a0 = 0.f, a1 = 0.f;
#pragma unroll
      for (int c = 0; c < 16; ++c) {
        float4 wv = w[c];
        a0 = fmaf(wv.x, xr[c].x, a0);
        a1 = fmaf(wv.y, xr[c].y, a1);
        a0 = fmaf(wv.z, xr[c].z, a0);
        a1 = fmaf(wv.w, xr[c].w, a1);
      }
      tile[e * 132 + rc * 32 + rl] = a0 + a1 + cc[rbase + rl];
    }
    __syncthreads();
    {
      const int c  = tid & 31;
      const int bq = tid >> 5;
#pragma unroll
      for (int bp = 0; bp < 8; ++bp) {
        const int bb = bp * 8 + bq;
        float4 v = *(const float4*)&tile[bb * 132 + c * 4];
        *(float4*)(gh + (size_t)(b0 + bb) * 512 + (r0 + p * 128) + c * 4) = v;
      }
    }
    __syncthreads();
  }
}

// ---------------------------------------------------------------------------
// K2: per-element setup. One wave per element, 4 elements/block.
// A is streamed COALESCED (wave reads 16x1KB contiguous chunks); partial dots
// reduced across the 16-lane row group, parked in LDS.
// ---------------------------------------------------------------------------
#define XOFF  0
#define BVOFF 64
#define BOFF  72
#define GHOFF (72 + 1024)          // 1096, gh rows padded to 68
#define LGOFF (1096 + 544)         // 1640, Lg rows padded to 20
#define AXOFF (1640 + 160)         // 1800, ax[64]
#define ESTR  (1800 + 64)          // 1864 floats per element

__global__ __launch_bounds__(256) void cbf_k2_setup(
    const float* __restrict__ X, const float* __restrict__ Abat,
    const float* __restrict__ Bbat, const float* __restrict__ cc,
    const float* __restrict__ dc, const float* __restrict__ a_des,
    const float* __restrict__ gh, float* __restrict__ S_ws,
    float* __restrict__ LgT_ws, float* __restrict__ qu_ws) {
  __shared__ float smem[4 * ESTR];
  const int tid  = threadIdx.x;
  const int sub  = tid >> 6;
  const int lane = tid & 63;
  const int b    = blockIdx.x * 4 + sub;
  float* sm = smem + sub * ESTR;

  // phase 0: stage x and B (coalesced) into LDS
  const float xi = X[(size_t)b * 64 + lane];
  sm[XOFF + lane] = xi;
  {
    const float4* bp = (const float4*)(Bbat + (size_t)b * 1024);
#pragma unroll
    for (int n = 0; n < 4; ++n) {
      float4 v = bp[n * 64 + lane];
      *(float4*)&sm[BOFF + n * 256 + lane * 4] = v;
    }
  }
  __syncthreads();

  // phase A: Ax with fully coalesced A reads.
  // chunk n: lane holds A[row = n*4 + lane/16][col = (lane&15)*4 .. +3]
  {
    const float4* ap = (const float4*)(Abat + (size_t)b * 4096);
    const int cg = lane & 15;
    const int rg = lane >> 4;
    const float4 xv = *(const float4*)&sm[XOFF + cg * 4];
#pragma unroll
    for (int n = 0; n < 16; ++n) {
      float4 av = ap[n * 64 + lane];
      float p = av.x * xv.x + av.y * xv.y + av.z * xv.z + av.w * xv.w;
      p += __shfl_xor(p, 1);
      p += __shfl_xor(p, 2);
      p += __shfl_xor(p, 4);
      p += __shfl_xor(p, 8);
      if (cg == 0) sm[AXOFF + n * 4 + rg] = p;
    }
  }
  __syncthreads();
  const float ax = sm[AXOFF + lane];

  // phase B: per-m reductions -> bvec ; stage gh rows in LDS
#pragma unroll
  for (int m = 0; m < 8; ++m) {
    float ghm = gh[(size_t)b * 512 + m * 64 + lane];
    float ccm = cc[m * 64 + lane];
    sm[GHOFF + m * 68 + lane] = ghm;
    float p1 = xi * ghm;   // -> x . gh_m
    float p2 = ax * ghm;   // -> Ax . gh_m
    float p3 = ccm * xi;   // -> cc_m . x
#pragma unroll
    for (int s = 1; s < 64; s <<= 1) {
      p1 += __shfl_xor(p1, s);
      p2 += __shfl_xor(p2, s);
      p3 += __shfl_xor(p3, s);
    }
    // g = 0.5*(x.gh + cc.x) - dc ; bvec = (Ax.gh) + g
    float g  = 0.5f * (p1 + p3) - dc[m];
    float bv = p2 + g;
    if (lane == 0) sm[BVOFF + m] = bv;
  }
  __syncthreads();

  // phase C: Lg[m][a] = -sum_i gh[m][i] * B[i][a] ; lane=(m, a-pair)
  const int mq  = lane >> 3;
  const int ap2 = lane & 7;
  float acc0 = 0.f, acc1 = 0.f;
#pragma unroll
  for (int c = 0; c < 16; ++c) {
    float4 gv = *(const float4*)&sm[GHOFF + mq * 68 + 4 * c];
#pragma unroll
    for (int n = 0; n < 4; ++n) {
      float2 bv2 = *(const float2*)&sm[BOFF + (4 * c + n) * 16 + 2 * ap2];
      float gvn = (n == 0) ? gv.x : ((n == 1) ? gv.y : ((n == 2) ? gv.z : gv.w));
      acc0 = fmaf(gvn, bv2.x, acc0);
      acc1 = fmaf(gvn, bv2.y, acc1);
    }
  }
  const float lg0 = -acc0, lg1 = -acc1;
  LgT_ws[(size_t)b * 128 + (2 * ap2) * 8 + mq]     = lg0;  // LgT[a][m]
  LgT_ws[(size_t)b * 128 + (2 * ap2 + 1) * 8 + mq] = lg1;
  sm[LGOFF + mq * 20 + 2 * ap2]     = lg0;
  sm[LGOFF + mq * 20 + 2 * ap2 + 1] = lg1;
  __syncthreads();

  // phase D: S[k][l] = 0.5 * sum_a Lg[k][a]*Lg[l][a] ; lane=(k,l)
  const int kq = lane >> 3;
  const int lq = lane & 7;
  float s = 0.f;
#pragma unroll
  for (int c = 0; c < 4; ++c) {
    float4 ka = *(const float4*)&sm[LGOFF + kq * 20 + 4 * c];
    float4 la = *(const float4*)&sm[LGOFF + lq * 20 + 4 * c];
    s = fmaf(ka.x, la.x, s);
    s = fmaf(ka.y, la.y, s);
    s = fmaf(ka.z, la.z, s);
    s = fmaf(ka.w, la.w, s);
  }
  S_ws[(size_t)b * 64 + kq * 8 + lq] = 0.5f * s;

  // phase E: qu[k] = bvec[k] - sum_a Lg[k][a]*a_des[a]
  float2 ad2 = *(const float2*)(a_des + (size_t)b * 16 + 2 * lq);
  float2 kg  = *(const float2*)&sm[LGOFF + kq * 20 + 2 * lq];
  float p = kg.x * ad2.x + kg.y * ad2.y;
  p += __shfl_xor(p, 1);
  p += __shfl_xor(p, 2);
  p += __shfl_xor(p, 4);
  float quv = sm[BVOFF + kq] - p;
  if (lq == 0) qu_ws[(size_t)b * 8 + kq] = quv;
}

// ---------------------------------------------------------------------------
// K3: dual FISTA, 4 lanes per element; lane q owns rows q and q+4 of S.
// All cross-lane traffic is DPP quad_perm on the VALU pipe (zero DS ops).
// M = [[S+cI, cI],[cI,cI]] -> grad_u = S yu + c(yu+yv) - qu ; grad_v = c(yu+yv)
// lambda_max(M) = ((2c+mu)+sqrt(4c^2+mu^2))/2, mu = lambda_max(S) (power it.)
// ---------------------------------------------------------------------------
__global__ __launch_bounds__(256) void cbf_k3_fista(
    const float* __restrict__ S_ws, const float* __restrict__ qu_ws,
    const float* __restrict__ LgT_ws, const float* __restrict__ a_des,
    float* __restrict__ out) {
  const int gt = blockIdx.x * 256 + threadIdx.x;
  const int e  = gt >> 2;
  const int q  = gt & 3;

  const float4* Sp = (const float4*)(S_ws + (size_t)e * 64);
  const float4 sl0 = Sp[q * 2],       sl1 = Sp[q * 2 + 1];        // row q
  const float4 sh0 = Sp[(q + 4) * 2], sh1 = Sp[(q + 4) * 2 + 1];  // row q+4
  const float qu_lo = qu_ws[(size_t)e * 8 + q];
  const float qu_hi = qu_ws[(size_t)e * 8 + q + 4];

#define MV(ylo, yhi, alo, ahi) do {                                          \
    float b0 = fdpp<0x00>(ylo), b1 = fdpp<0x55>(ylo);                        \
    float b2 = fdpp<0xAA>(ylo), b3 = fdpp<0xFF>(ylo);                        \
    float b4 = fdpp<0x00>(yhi), b5 = fdpp<0x55>(yhi);                        \
    float b6 = fdpp<0xAA>(yhi), b7 = fdpp<0xFF>(yhi);                        \
    float t0 = sl0.x * b0, t1 = sl0.y * b1;                                  \
    t0 = fmaf(sl0.z, b2, t0); t1 = fmaf(sl0.w, b3, t1);                      \
    t0 = fmaf(sl1.x, b4, t0); t1 = fmaf(sl1.y, b5, t1);                      \
    t0 = fmaf(sl1.z, b6, t0); t1 = fmaf(sl1.w, b7, t1);                      \
    alo = t0 + t1;                                                           \
    float u0 = sh0.x * b0, u1 = sh0.y * b1;                                  \
    u0 = fmaf(sh0.z, b2, u0); u1 = fmaf(sh0.w, b3, u1);                      \
    u0 = fmaf(sh1.x, b4, u0); u1 = fmaf(sh1.y, b5, u1);                      \
    u0 = fmaf(sh1.z, b6, u0); u1 = fmaf(sh1.w, b7, u1);                      \
    ahi = u0 + u1;                                                           \
  } while (0)

  // power iteration for mu = lambda_max(S)
  float vl = 1.f, vh = 1.f, svl, svh;
#pragma unroll 4
  for (int it = 0; it < 40; ++it) {
    MV(vl, vh, svl, svh);
    float am = fmaxf(fabsf(svl), fabsf(svh));
    am = fmaxf(am, fdpp<0xB1>(am));   // xor 1 within quad
    am = fmaxf(am, fdpp<0x4E>(am));   // xor 2 within quad
    float r = 1.f / fmaxf(am, 1e-30f);
    vl = svl * r; vh = svh * r;
  }
  MV(vl, vh, svl, svh);
  float num = vl * svl + vh * svh;
  float den = vl * vl + vh * vh;
  num += fdpp<0xB1>(num); den += fdpp<0xB1>(den);
  num += fdpp<0x4E>(num); den += fdpp<0x4E>(den);
  float mu = fmaxf((num / fmaxf(den, 1e-30f)) * 1.001f, 0.f);
  const float lmax = 0.5f * ((0.1f + mu) + sqrtf(fmaf(mu, mu, 0.01f)));
  const float t = 1.0f / (lmax + 1e-6f);

  // FISTA, 250 iterations — pure VALU
  float yul = 0.f, yuh = 0.f, yvl = 0.f, yvh = 0.f;
  float lul = 0.f, luh = 0.f, lvl_ = 0.f, lvh = 0.f;
#pragma unroll 5
  for (int it = 0; it < 250; ++it) {
    const float beta = BETAS.b[it];
    const float wl = 0.05f * (yul + yvl);   // c*(yu+yv) = grad_v
    const float wh = 0.05f * (yuh + yvh);
    float al, ah;
    MV(yul, yuh, al, ah);
    const float gul = al + wl - qu_lo;
    const float guh = ah + wh - qu_hi;
    const float lunl = fmaxf(fmaf(-t, gul, yul), 0.f);
    const float lunh = fmaxf(fmaf(-t, guh, yuh), 0.f);
    const float lvnl = fmaxf(fmaf(-t, wl, yvl), 0.f);
    const float lvnh = fmaxf(fmaf(-t, wh, yvh), 0.f);
    yul = fmaf(beta, lunl - lul, lunl); lul = lunl;
    yuh = fmaf(beta, lunh - luh, lunh); luh = lunh;
    yvl = fmaf(beta, lvnl - lvl_, lvnl); lvl_ = lvnl;
    yvh = fmaf(beta, lvnh - lvh, lvnh); lvh = lvnh;
  }
#undef MV

  // primal recovery: lane q computes a[q*4 .. q*4+3]
  const float l0 = fdpp<0x00>(lul), l1 = fdpp<0x55>(lul);
  const float l2 = fdpp<0xAA>(lul), l3 = fdpp<0xFF>(lul);
  const float l4 = fdpp<0x00>(luh), l5 = fdpp<0x55>(luh);
  const float l6 = fdpp<0xAA>(luh), l7 = fdpp<0xFF>(luh);
  const float4* Lp = (const float4*)(LgT_ws + (size_t)e * 128 + q * 32);
  const float4 ad  = *(const float4*)(a_des + (size_t)e * 16 + q * 4);
  float o[4];
#pragma unroll
  for (int j = 0; j < 4; ++j) {
    float4 ga = Lp[j * 2], gb = Lp[j * 2 + 1];   // LgT[a = q*4+j][0..7]
    float s = ga.x * l0 + ga.y * l1 + ga.z * l2 + ga.w * l3
            + gb.x * l4 + gb.y * l5 + gb.z * l6 + gb.w * l7;
    o[j] = 0.5f * s;
  }
  float4 ov;
  ov.x = ad.x + o[0]; ov.y = ad.y + o[1];
  ov.z = ad.z + o[2]; ov.w = ad.w + o[3];
  *(float4*)(out + (size_t)e * 16 + q * 4) = ov;
}

// ---------------------------------------------------------------------------
extern "C" void kernel_launch(void* const* d_in, const int* in_sizes, int n_in,
                              void* d_out, int out_size, void* d_ws, size_t ws_size,
                              hipStream_t stream) {
  (void)in_sizes; (void)n_in; (void)out_size; (void)ws_size;
  const float* a_des = (const float*)d_in[0];
  const float* x     = (const float*)d_in[1];
  const float* A     = (const float*)d_in[2];
  const float* B     = (const float*)d_in[3];
  const float* Qc    = (const float*)d_in[4];
  const float* cc    = (const float*)d_in[5];
  const float* dc    = (const float*)d_in[6];
  float* out = (float*)d_out;

  // workspace layout (floats): gh 16384*512 | S 16384*64 | LgT 16384*128 | qu 16384*8
  float* gh  = (float*)d_ws;
  float* S   = gh  + (size_t)NBATCH * 512;
  float* LgT = S   + (size_t)NBATCH * 64;
  float* qu  = LgT + (size_t)NBATCH * 128;

  hipLaunchKernelGGL(cbf_k1_gh, dim3(512), dim3(256), 0, stream, Qc, cc, x, gh);
  hipLaunchKernelGGL(cbf_k2_setup, dim3(4096), dim3(256), 0, stream,
                     x, A, B, cc, dc, a_des, gh, S, LgT, qu);
  hipLaunchKernelGGL(cbf_k3_fista, dim3(256), dim3(256), 0, stream,
                     S, qu, LgT, a_des, out);
}

// Round 4
// 523.946 us; speedup vs baseline: 1.0712x; 1.0314x over previous
//
#include <hip/hip_runtime.h>
#include <cstddef>

// Problem constants
#define NBATCH 16384
// XD=64, AD=16, NC=8, PEN=10 -> c = 1/(2*PEN) = 0.05, DELTA=1, ITERS=250

// ---------------------------------------------------------------------------
// Compile-time FISTA momentum coefficients beta_i = (t_i - 1)/t_{i+1}
// ---------------------------------------------------------------------------
struct Betas {
  float b[250];
  static constexpr double csqrt(double x) {
    double g = x > 1.0 ? x : 1.0;
    for (int i = 0; i < 64; ++i) g = 0.5 * (g + x / g);
    return g;
  }
  constexpr Betas() : b{} {
    double tk = 1.0;
    for (int i = 0; i < 250; ++i) {
      double tk1 = 0.5 * (1.0 + csqrt(1.0 + 4.0 * tk * tk));
      b[i] = (float)((tk - 1.0) / tk1);
      tk = tk1;
    }
  }
};
__device__ constexpr Betas BETAS{};

// DPP helpers (VALU pipe — zero DS ops).
// quad_perm broadcasts: 0x00/0x55/0xAA/0xFF ; quad xor1=0xB1, xor2=0x4E
// row_ror:N = 0x120|N. NOTE: only direction-agnostic patterns are safe:
// full 16-lane rotate-sums (1,2,4,8) work for either ror direction; partial
// rotate-sums (e.g. 8-group via ror 1,2,4) are direction-dependent and were
// a correctness bug in R3 — use __shfl_xor for sub-row groups instead.
template <int CTRL>
__device__ __forceinline__ float fdpp(float v) {
  return __int_as_float(
      __builtin_amdgcn_mov_dpp(__float_as_int(v), CTRL, 0xF, 0xF, true));
}
// rotate-sum over a 16-lane row: every lane ends with the row total
__device__ __forceinline__ float rowsum16(float p) {
  p += fdpp<0x121>(p);
  p += fdpp<0x122>(p);
  p += fdpp<0x124>(p);
  p += fdpp<0x128>(p);
  return p;
}

// ---------------------------------------------------------------------------
// K1: gh[b][r] = Qc_flat[r][:] . x[b][:] + cc_flat[r],  r = m*64+i  (512 rows)
// Thread = (batch element, row chunk); Qc rows wave-uniform -> s_load
// broadcast. LDS transpose for coalesced [b][r] stores.
// ---------------------------------------------------------------------------
__global__ __launch_bounds__(256) void cbf_k1_gh(
    const float* __restrict__ Qc, const float* __restrict__ cc,
    const float* __restrict__ X, float* __restrict__ gh) {
  __shared__ float tile[64 * 132];  // [b-local 64][r-local 128 + pad 4]
  const int tid = threadIdx.x;
  const int e   = tid & 63;
  const int rc  = tid >> 6;
  const int b0  = (blockIdx.x & 255) * 64;
  const int r0  = (blockIdx.x >> 8) * 256;

  float4 xr[16];
  const float4* xp = (const float4*)(X + (size_t)(b0 + e) * 64);
#pragma unroll
  for (int c = 0; c < 16; ++c) xr[c] = xp[c];

  const int rcu = __builtin_amdgcn_readfirstlane(rc);

  for (int p = 0; p < 2; ++p) {
    const int rbase = r0 + p * 128 + rcu * 32;
    const float* wbase = Qc + (size_t)rbase * 64;
#pragma unroll 4
    for (int rl = 0; rl < 32; ++rl) {
      const float4* w = (const float4*)(wbase + rl * 64);
      float a0 = 0.f, a1 = 0.f;
#pragma unroll
      for (int c = 0; c < 16; ++c) {
        float4 wv = w[c];
        a0 = fmaf(wv.x, xr[c].x, a0);
        a1 = fmaf(wv.y, xr[c].y, a1);
        a0 = fmaf(wv.z, xr[c].z, a0);
        a1 = fmaf(wv.w, xr[c].w, a1);
      }
      tile[e * 132 + rc * 32 + rl] = a0 + a1 + cc[rbase + rl];
    }
    __syncthreads();
    {
      const int c  = tid & 31;
      const int bq = tid >> 5;
#pragma unroll
      for (int bp = 0; bp < 8; ++bp) {
        const int bb = bp * 8 + bq;
        float4 v = *(const float4*)&tile[bb * 132 + c * 4];
        *(float4*)(gh + (size_t)(b0 + bb) * 512 + (r0 + p * 128) + c * 4) = v;
      }
    }
    __syncthreads();
  }
}

// ---------------------------------------------------------------------------
// K2: per-element setup, one wave per element, 4 elements/block.
// Phase A uses DPP full-row rotate-sums (direction-safe); sub-row group
// reductions use __shfl_xor (involutive, direction-unambiguous).
// ---------------------------------------------------------------------------
#define XOFF  0
#define BVOFF 64
#define BOFF  72
#define GHOFF (72 + 1024)          // 1096, gh rows padded to 68
#define LGOFF (1096 + 544)         // 1640, Lg rows padded to 20
#define AXOFF (1640 + 160)         // 1800, ax[64]
#define ESTR  (1800 + 64)          // 1864 floats per element

__global__ __launch_bounds__(256) void cbf_k2_setup(
    const float* __restrict__ X, const float* __restrict__ Abat,
    const float* __restrict__ Bbat, const float* __restrict__ cc,
    const float* __restrict__ dc, const float* __restrict__ a_des,
    const float* __restrict__ gh, float* __restrict__ S_ws,
    float* __restrict__ LgT_ws, float* __restrict__ qu_ws) {
  __shared__ float smem[4 * ESTR];
  const int tid  = threadIdx.x;
  const int sub  = tid >> 6;
  const int lane = tid & 63;
  const int b    = blockIdx.x * 4 + sub;
  float* sm = smem + sub * ESTR;

  // ---- stage: x, B [i][a], gh (padded rows) -> LDS --------------------------
  const float xi = X[(size_t)b * 64 + lane];
  sm[XOFF + lane] = xi;
  {
    const float4* bp = (const float4*)(Bbat + (size_t)b * 1024);
#pragma unroll
    for (int n = 0; n < 4; ++n) {
      float4 v = bp[n * 64 + lane];
      *(float4*)&sm[BOFF + n * 256 + lane * 4] = v;
    }
  }
  {
    const float4* gp = (const float4*)(gh + (size_t)b * 512);
    float4 g0 = gp[lane];        // floats [lane*4, +4)
    float4 g1 = gp[64 + lane];   // floats [256+lane*4, +4)
    const int f0 = lane * 4, f1 = 256 + lane * 4;
    *(float4*)&sm[GHOFF + (f0 >> 6) * 68 + (f0 & 63)] = g0;
    *(float4*)&sm[GHOFF + (f1 >> 6) * 68 + (f1 & 63)] = g1;
  }
  __syncthreads();

  // ---- phase A: Ax, coalesced A stream + DPP full-row reductions ------------
  {
    const float4* ap = (const float4*)(Abat + (size_t)b * 4096);
    const int cg = lane & 15;      // column group (16-lane DPP row)
    const int rg = lane >> 4;      // row-in-chunk
    const float4 xv = *(const float4*)&sm[XOFF + cg * 4];
#pragma unroll
    for (int n = 0; n < 16; ++n) {
      float4 av = ap[n * 64 + lane];
      float p = av.x * xv.x + av.y * xv.y + av.z * xv.z + av.w * xv.w;
      p = rowsum16(p);                       // VALU-only, direction-safe
      if (cg == 0) sm[AXOFF + n * 4 + rg] = p;
    }
  }
  __syncthreads();

  // ---- phase B: bvec[m] via 8-wide partial dots + xor group sums ------------
  {
    const int m  = lane >> 3;
    const int ig = lane & 7;
    const float4 ghA = *(const float4*)&sm[GHOFF + m * 68 + ig * 8];
    const float4 ghB = *(const float4*)&sm[GHOFF + m * 68 + ig * 8 + 4];
    const float4 xA  = *(const float4*)&sm[XOFF + ig * 8];
    const float4 xB  = *(const float4*)&sm[XOFF + ig * 8 + 4];
    const float4 axA = *(const float4*)&sm[AXOFF + ig * 8];
    const float4 axB = *(const float4*)&sm[AXOFF + ig * 8 + 4];
    const float4 ccA = *(const float4*)(cc + m * 64 + ig * 8);
    const float4 ccB = *(const float4*)(cc + m * 64 + ig * 8 + 4);
    float p1 = ghA.x * xA.x + ghA.y * xA.y + ghA.z * xA.z + ghA.w * xA.w
             + ghB.x * xB.x + ghB.y * xB.y + ghB.z * xB.z + ghB.w * xB.w;
    float p2 = ghA.x * axA.x + ghA.y * axA.y + ghA.z * axA.z + ghA.w * axA.w
             + ghB.x * axB.x + ghB.y * axB.y + ghB.z * axB.z + ghB.w * axB.w;
    float p3 = ccA.x * xA.x + ccA.y * xA.y + ccA.z * xA.z + ccA.w * xA.w
             + ccB.x * xB.x + ccB.y * xB.y + ccB.z * xB.z + ccB.w * xB.w;
    p1 += __shfl_xor(p1, 1); p1 += __shfl_xor(p1, 2); p1 += __shfl_xor(p1, 4);
    p2 += __shfl_xor(p2, 1); p2 += __shfl_xor(p2, 2); p2 += __shfl_xor(p2, 4);
    p3 += __shfl_xor(p3, 1); p3 += __shfl_xor(p3, 2); p3 += __shfl_xor(p3, 4);
    if (ig == 0) {
      // g = 0.5*(x.gh + cc.x) - dc ; bvec = (Ax.gh) + g
      sm[BVOFF + m] = p2 + 0.5f * (p1 + p3) - dc[m];
    }
  }

  // ---- phase C: Lg[m][a] = -sum_i gh[m][i]*B[i][a] --------------------------
  const int mq  = lane >> 3;
  const int ap2 = lane & 7;
  {
    float acc0 = 0.f, acc1 = 0.f;
#pragma unroll
    for (int c = 0; c < 16; ++c) {
      float4 gv = *(const float4*)&sm[GHOFF + mq * 68 + 4 * c];
#pragma unroll
      for (int n = 0; n < 4; ++n) {
        float2 bv2 = *(const float2*)&sm[BOFF + (4 * c + n) * 16 + 2 * ap2];
        float gvn = (n == 0) ? gv.x : ((n == 1) ? gv.y : ((n == 2) ? gv.z : gv.w));
        acc0 = fmaf(gvn, bv2.x, acc0);
        acc1 = fmaf(gvn, bv2.y, acc1);
      }
    }
    const float lg0 = -acc0, lg1 = -acc1;
    LgT_ws[(size_t)b * 128 + (2 * ap2) * 8 + mq]     = lg0;  // LgT[a][m]
    LgT_ws[(size_t)b * 128 + (2 * ap2 + 1) * 8 + mq] = lg1;
    sm[LGOFF + mq * 20 + 2 * ap2]     = lg0;
    sm[LGOFF + mq * 20 + 2 * ap2 + 1] = lg1;
  }
  __syncthreads();

  // ---- phase D: S[k][l] = 0.5 * <Lg_k, Lg_l> --------------------------------
  const int kq = lane >> 3;
  const int lq = lane & 7;
  {
    float s = 0.f;
#pragma unroll
    for (int c = 0; c < 4; ++c) {
      float4 ka = *(const float4*)&sm[LGOFF + kq * 20 + 4 * c];
      float4 la = *(const float4*)&sm[LGOFF + lq * 20 + 4 * c];
      s = fmaf(ka.x, la.x, s);
      s = fmaf(ka.y, la.y, s);
      s = fmaf(ka.z, la.z, s);
      s = fmaf(ka.w, la.w, s);
    }
    S_ws[(size_t)b * 64 + kq * 8 + lq] = 0.5f * s;
  }

  // ---- phase E: qu[k] = bvec[k] - <Lg_k, a_des> (xor group sum) -------------
  {
    float2 ad2 = *(const float2*)(a_des + (size_t)b * 16 + 2 * lq);
    float2 kg  = *(const float2*)&sm[LGOFF + kq * 20 + 2 * lq];
    float p = kg.x * ad2.x + kg.y * ad2.y;
    p += __shfl_xor(p, 1);
    p += __shfl_xor(p, 2);
    p += __shfl_xor(p, 4);
    if (lq == 0) qu_ws[(size_t)b * 8 + kq] = sm[BVOFF + kq] - p;
  }
}

// ---------------------------------------------------------------------------
// K3: dual FISTA, 4 lanes per element; lane q owns rows q and q+4 of S.
// All cross-lane traffic is DPP quad_perm on the VALU pipe (zero DS ops).
// M = [[S+cI, cI],[cI,cI]] -> grad_u = S yu + c(yu+yv) - qu ; grad_v = c(yu+yv)
// lambda_max(M) = ((2c+mu)+sqrt(4c^2+mu^2))/2, mu = lambda_max(S) (power it.)
// ---------------------------------------------------------------------------
__global__ __launch_bounds__(256) void cbf_k3_fista(
    const float* __restrict__ S_ws, const float* __restrict__ qu_ws,
    const float* __restrict__ LgT_ws, const float* __restrict__ a_des,
    float* __restrict__ out) {
  const int gt = blockIdx.x * 256 + threadIdx.x;
  const int e  = gt >> 2;
  const int q  = gt & 3;

  const float4* Sp = (const float4*)(S_ws + (size_t)e * 64);
  const float4 sl0 = Sp[q * 2],       sl1 = Sp[q * 2 + 1];        // row q
  const float4 sh0 = Sp[(q + 4) * 2], sh1 = Sp[(q + 4) * 2 + 1];  // row q+4
  const float qu_lo = qu_ws[(size_t)e * 8 + q];
  const float qu_hi = qu_ws[(size_t)e * 8 + q + 4];

#define MV(ylo, yhi, alo, ahi) do {                                          \
    float b0 = fdpp<0x00>(ylo), b1 = fdpp<0x55>(ylo);                        \
    float b2 = fdpp<0xAA>(ylo), b3 = fdpp<0xFF>(ylo);                        \
    float b4 = fdpp<0x00>(yhi), b5 = fdpp<0x55>(yhi);                        \
    float b6 = fdpp<0xAA>(yhi), b7 = fdpp<0xFF>(yhi);                        \
    float t0 = sl0.x * b0, t1 = sl0.y * b1;                                  \
    t0 = fmaf(sl0.z, b2, t0); t1 = fmaf(sl0.w, b3, t1);                      \
    t0 = fmaf(sl1.x, b4, t0); t1 = fmaf(sl1.y, b5, t1);                      \
    t0 = fmaf(sl1.z, b6, t0); t1 = fmaf(sl1.w, b7, t1);                      \
    alo = t0 + t1;                                                           \
    float u0 = sh0.x * b0, u1 = sh0.y * b1;                                  \
    u0 = fmaf(sh0.z, b2, u0); u1 = fmaf(sh0.w, b3, u1);                      \
    u0 = fmaf(sh1.x, b4, u0); u1 = fmaf(sh1.y, b5, u1);                      \
    u0 = fmaf(sh1.z, b6, u0); u1 = fmaf(sh1.w, b7, u1);                      \
    ahi = u0 + u1;                                                           \
  } while (0)

  // power iteration for mu = lambda_max(S)
  float vl = 1.f, vh = 1.f, svl, svh;
#pragma unroll 4
  for (int it = 0; it < 40; ++it) {
    MV(vl, vh, svl, svh);
    float am = fmaxf(fabsf(svl), fabsf(svh));
    am = fmaxf(am, fdpp<0xB1>(am));   // xor 1 within quad
    am = fmaxf(am, fdpp<0x4E>(am));   // xor 2 within quad
    float r = 1.f / fmaxf(am, 1e-30f);
    vl = svl * r; vh = svh * r;
  }
  MV(vl, vh, svl, svh);
  float num = vl * svl + vh * svh;
  float den = vl * vl + vh * vh;
  num += fdpp<0xB1>(num); den += fdpp<0xB1>(den);
  num += fdpp<0x4E>(num); den += fdpp<0x4E>(den);
  float mu = fmaxf((num / fmaxf(den, 1e-30f)) * 1.001f, 0.f);
  const float lmax = 0.5f * ((0.1f + mu) + sqrtf(fmaf(mu, mu, 0.01f)));
  const float t = 1.0f / (lmax + 1e-6f);

  // FISTA, 250 iterations — pure VALU
  float yul = 0.f, yuh = 0.f, yvl = 0.f, yvh = 0.f;
  float lul = 0.f, luh = 0.f, lvl_ = 0.f, lvh = 0.f;
#pragma unroll 5
  for (int it = 0; it < 250; ++it) {
    const float beta = BETAS.b[it];
    const float wl = 0.05f * (yul + yvl);   // c*(yu+yv) = grad_v
    const float wh = 0.05f * (yuh + yvh);
    float al, ah;
    MV(yul, yuh, al, ah);
    const float gul = al + wl - qu_lo;
    const float guh = ah + wh - qu_hi;
    const float lunl = fmaxf(fmaf(-t, gul, yul), 0.f);
    const float lunh = fmaxf(fmaf(-t, guh, yuh), 0.f);
    const float lvnl = fmaxf(fmaf(-t, wl, yvl), 0.f);
    const float lvnh = fmaxf(fmaf(-t, wh, yvh), 0.f);
    yul = fmaf(beta, lunl - lul, lunl); lul = lunl;
    yuh = fmaf(beta, lunh - luh, lunh); luh = lunh;
    yvl = fmaf(beta, lvnl - lvl_, lvnl); lvl_ = lvnl;
    yvh = fmaf(beta, lvnh - lvh, lvnh); lvh = lvnh;
  }
#undef MV

  // primal recovery: lane q computes a[q*4 .. q*4+3]
  const float l0 = fdpp<0x00>(lul), l1 = fdpp<0x55>(lul);
  const float l2 = fdpp<0xAA>(lul), l3 = fdpp<0xFF>(lul);
  const float l4 = fdpp<0x00>(luh), l5 = fdpp<0x55>(luh);
  const float l6 = fdpp<0xAA>(luh), l7 = fdpp<0xFF>(luh);
  const float4* Lp = (const float4*)(LgT_ws + (size_t)e * 128 + q * 32);
  const float4 ad  = *(const float4*)(a_des + (size_t)e * 16 + q * 4);
  float o[4];
#pragma unroll
  for (int j = 0; j < 4; ++j) {
    float4 ga = Lp[j * 2], gb = Lp[j * 2 + 1];   // LgT[a = q*4+j][0..7]
    float s = ga.x * l0 + ga.y * l1 + ga.z * l2 + ga.w * l3
            + gb.x * l4 + gb.y * l5 + gb.z * l6 + gb.w * l7;
    o[j] = 0.5f * s;
  }
  float4 ov;
  ov.x = ad.x + o[0]; ov.y = ad.y + o[1];
  ov.z = ad.z + o[2]; ov.w = ad.w + o[3];
  *(float4*)(out + (size_t)e * 16 + q * 4) = ov;
}

// ---------------------------------------------------------------------------
extern "C" void kernel_launch(void* const* d_in, const int* in_sizes, int n_in,
                              void* d_out, int out_size, void* d_ws, size_t ws_size,
                              hipStream_t stream) {
  (void)in_sizes; (void)n_in; (void)out_size; (void)ws_size;
  const float* a_des = (const float*)d_in[0];
  const float* x     = (const float*)d_in[1];
  const float* A     = (const float*)d_in[2];
  const float* B     = (const float*)d_in[3];
  const float* Qc    = (const float*)d_in[4];
  const float* cc    = (const float*)d_in[5];
  const float* dc    = (const float*)d_in[6];
  float* out = (float*)d_out;

  // workspace layout (floats): gh 16384*512 | S 16384*64 | LgT 16384*128 | qu 16384*8
  float* gh  = (float*)d_ws;
  float* S   = gh  + (size_t)NBATCH * 512;
  float* LgT = S   + (size_t)NBATCH * 64;
  float* qu  = LgT + (size_t)NBATCH * 128;

  hipLaunchKernelGGL(cbf_k1_gh, dim3(512), dim3(256), 0, stream, Qc, cc, x, gh);
  hipLaunchKernelGGL(cbf_k2_setup, dim3(4096), dim3(256), 0, stream,
                     x, A, B, cc, dc, a_des, gh, S, LgT, qu);
  hipLaunchKernelGGL(cbf_k3_fista, dim3(256), dim3(256), 0, stream,
                     S, qu, LgT, a_des, out);
}